// Round 10
// baseline (194.620 us; speedup 1.0000x reference)
//
#include <hip/hip_runtime.h>
#include <stdint.h>

// ColBERT MaxSim on MI355X (gfx950), round 10.
// scores[b,c] = sum_n max_s dot(qs[b,n,:], ps[c,s,:])
// qs: (64, 32, 128) f32, ps: (64, 1024, 128) f32, out: (64, 64) f32.
//
// R9 ledger: qfr parked in AGPRs (VGPR=112, no scratch) — fine, MFMA reads
// AGPRs. 2 waves/SIMD as designed. Issue-time demand ~7 us, BW demand far
// under ceilings, yet dur 53 us at 40% combined busy => exposed load latency:
// 1-tile-deep double buffer covers ~215 cyc but L2 latency (32 CUs/XCD in
// near-lockstep on the same 2 MB P_c) is ~500-900 cyc.
// R10: prefetch depth 4 (rolling abuf[4][4], 64 VGPRs): each tile's loads get
// ~3 tile-computes (~600+ cyc) of cover. Everything else unchanged from R9.

typedef __bf16 bf16x8 __attribute__((ext_vector_type(8)));
typedef float floatx4 __attribute__((ext_vector_type(4)));

#define QS_N (64u * 32u * 128u)    // 262144
#define PS_N (64u * 1024u * 128u)  // 8388608

__device__ inline unsigned short f2bf(float f) {
  union { float f; uint32_t u; } x{f};
  uint32_t r = (x.u + 0x7FFFu + ((x.u >> 16) & 1u)) >> 16;  // RNE
  return (unsigned short)r;
}

// Fused cvt: first QS_N/4 float4s from qs, rest from ps; qsb = ws, psb = ws + QS_N.
__global__ __launch_bounds__(256) void cvt_kernel(const float* __restrict__ qs,
                                                  const float* __restrict__ ps,
                                                  ushort* __restrict__ outb) {
  const int nq4 = QS_N / 4;
  const int n4 = (QS_N + PS_N) / 4;
  int i = blockIdx.x * 256 + threadIdx.x;
  if (i >= n4) return;
  float4 f;
  if (i < nq4) {
    f = ((const float4*)qs)[i];
  } else {
    f = ((const float4*)ps)[i - nq4];
  }
  ushort4 o;
  o.x = f2bf(f.x); o.y = f2bf(f.y); o.z = f2bf(f.z); o.w = f2bf(f.w);
  ((ushort4*)outb)[i] = o;
}

union FragU { uint4 u; bf16x8 v; };

__device__ inline bf16x8 as_frag(uint4 u) {
  FragU x;
  x.u = u;
  return x.v;
}

// Load 8 bf16 (16 B) as uint4, from pre-converted bf16 or on-the-fly from f32.
template <bool PRECVT>
__device__ inline uint4 load16(const void* p, int off) {
  if (PRECVT) {
    return *(const uint4*)((const ushort*)p + off);
  } else {
    const float* q = (const float*)p + off;
    float4 x = *(const float4*)q;
    float4 y = *(const float4*)(q + 4);
    union { ushort s[8]; uint4 u; } r;
    r.s[0] = f2bf(x.x); r.s[1] = f2bf(x.y); r.s[2] = f2bf(x.z); r.s[3] = f2bf(x.w);
    r.s[4] = f2bf(y.x); r.s[5] = f2bf(y.y); r.s[6] = f2bf(y.z); r.s[7] = f2bf(y.w);
    return r.u;
  }
}

#define ZERO4 {0, 0, 0, 0}

// One 16-row s-tile vs 4 query blocks x 2 n-halves: 32 MFMAs, 8 acc chains
// (4 regs each), 4 k-steps. A-frags in ABUF[0..3] (one per k-step).
#define TILE_COMPUTE(ABUF)                                                      \
  {                                                                             \
    floatx4 acc[4][2];                                                          \
    _Pragma("unroll") for (int b = 0; b < 4; ++b)                               \
      _Pragma("unroll") for (int h = 0; h < 2; ++h)                             \
        acc[b][h] = (floatx4)ZERO4;                                             \
    _Pragma("unroll") for (int k2 = 0; k2 < 4; ++k2) {                          \
      bf16x8 af = as_frag(ABUF[k2]);                                            \
      _Pragma("unroll") for (int b = 0; b < 4; ++b)                             \
        _Pragma("unroll") for (int h = 0; h < 2; ++h)                           \
          acc[b][h] = __builtin_amdgcn_mfma_f32_16x16x32_bf16(                  \
              af, as_frag(qfr[b][h][k2]), acc[b][h], 0, 0, 0);                  \
    }                                                                           \
    _Pragma("unroll") for (int b = 0; b < 4; ++b)                               \
      _Pragma("unroll") for (int h = 0; h < 2; ++h) {                           \
        float m = fmaxf(fmaxf(acc[b][h][0], acc[b][h][1]),                      \
                        fmaxf(acc[b][h][2], acc[b][h][3]));                     \
        vmax[b][h] = fmaxf(vmax[b][h], m);                                      \
      }                                                                         \
  }

template <bool PRECVT>
__global__ __launch_bounds__(256, 2) void maxsim_kernel(const void* __restrict__ qsv,
                                                        const void* __restrict__ psv,
                                                        float* __restrict__ out) {
  const int lane = threadIdx.x & 63;
  const int wave = threadIdx.x >> 6;

  // XCD-aware swizzle (R4: keeps P_c L2-resident, FETCH 66 -> 10 MB).
  const int xcd = blockIdx.x & 7;
  const int slot = blockIdx.x >> 3;
  const int c = xcd * 8 + (slot >> 4);
  const int bg = slot & 15;
  const int b0 = bg * 4;

  // 16x16x32 fragment lane pattern: idx16 = lane&15 (A: s-row, B: q-token),
  // koff = (lane>>4)*8; k-step k2 adds k2*32.
  const int idx16 = lane & 15;
  const int koff = (lane >> 4) * 8;

  // Q fragments: 4 b x 2 n-halves x 4 k-steps = 32 x 16 B = 128 regs.
  // Loaded from global ONCE, pinned per 32-bit component (opaque to remat;
  // compiler parks them in AGPRs — valid MFMA B-operand source on gfx950).
  uint4 qfr[4][2][4];
#pragma unroll
  for (int b = 0; b < 4; ++b)
#pragma unroll
    for (int h = 0; h < 2; ++h)
#pragma unroll
      for (int k2 = 0; k2 < 4; ++k2) {
        const int goff = ((b0 + b) * 32 + h * 16 + idx16) * 128 + k2 * 32 + koff;
        uint4 v = load16<PRECVT>(qsv, goff);
        asm volatile("" : "+v"(v.x), "+v"(v.y), "+v"(v.z), "+v"(v.w));
        qfr[b][h][k2] = v;
      }

  // Wave covers s in [wave*256, wave*256+256): 16 tiles of 16 doc tokens.
  const int pbase = (c * 1024 + wave * 256 + idx16) * 128 + koff;

  // Preload tiles 0..3 into the rolling buffer (depth-4 prefetch pipeline).
  uint4 abuf[4][4];
#pragma unroll
  for (int j = 0; j < 4; ++j)
#pragma unroll
    for (int k2 = 0; k2 < 4; ++k2)
      abuf[j][k2] = load16<PRECVT>(psv, pbase + j * 2048 + k2 * 32);

  float vmax[4][2];
#pragma unroll
  for (int b = 0; b < 4; ++b) {
    vmax[b][0] = -3.4e38f;
    vmax[b][1] = -3.4e38f;
  }

#pragma unroll 1
  for (int t = 0; t < 16; t += 4) {
#pragma unroll
    for (int j = 0; j < 4; ++j) {
      // Compute tile t+j from abuf[j] (its loads were issued 4 tiles ago:
      // ~3 tile-computes ~600 cyc of latency cover).
      TILE_COMPUTE(abuf[j])
      // Refill abuf[j] with tile t+j+4 (clamp at 15: redundant L1-hot re-read
      // on the last 4 tiles, cheaper than a branch).
      int tn = t + j + 4;
      if (tn > 15) tn = 15;
#pragma unroll
      for (int k2 = 0; k2 < 4; ++k2)
        abuf[j][k2] = load16<PRECVT>(psv, pbase + tn * 2048 + k2 * 32);
    }
  }

  // C/D: col = lane&15 (q-token), row = (lane>>4)*4 + reg (s). The 4 lane-quads
  // hold disjoint s-rows: fold with xor 16 and 32.
#pragma unroll
  for (int b = 0; b < 4; ++b)
#pragma unroll
    for (int h = 0; h < 2; ++h) {
      float v = vmax[b][h];
      v = fmaxf(v, __shfl_xor(v, 16, 64));
      v = fmaxf(v, __shfl_xor(v, 32, 64));
      vmax[b][h] = v;
    }

  // Cross-wave max, then sum over the 32 query tokens.
  __shared__ float red[4][4][32];  // [wave][b][n]
  if (lane < 16) {
#pragma unroll
    for (int b = 0; b < 4; ++b) {
      red[wave][b][lane] = vmax[b][0];
      red[wave][b][16 + lane] = vmax[b][1];
    }
  }
  __syncthreads();
  if (threadIdx.x < 128) {
    const int b = threadIdx.x >> 5;
    const int n = threadIdx.x & 31;
    float m = fmaxf(fmaxf(red[0][b][n], red[1][b][n]), fmaxf(red[2][b][n], red[3][b][n]));
#pragma unroll
    for (int o = 16; o > 0; o >>= 1) m += __shfl_xor(m, o, 32);
    if (n == 0) out[(b0 + b) * 64 + c] = m;
  }
}

extern "C" void kernel_launch(void* const* d_in, const int* in_sizes, int n_in,
                              void* d_out, int out_size, void* d_ws, size_t ws_size,
                              hipStream_t stream) {
  const float* qs = (const float*)d_in[0];
  const float* ps = (const float*)d_in[1];
  float* out = (float*)d_out;

  const size_t need = (QS_N + PS_N) * sizeof(ushort);  // 16.5 MiB

  if (ws_size >= need) {
    ushort* wsb = (ushort*)d_ws;
    const int n4 = (int)((QS_N + PS_N) / 4);
    cvt_kernel<<<(n4 + 255) / 256, 256, 0, stream>>>(qs, ps, wsb);
    maxsim_kernel<true><<<dim3(64 * 16), dim3(256), 0, stream>>>(wsb, wsb + QS_N, out);
  } else {
    maxsim_kernel<false><<<dim3(64 * 16), dim3(256), 0, stream>>>(qs, ps, out);
  }
}

// Round 11
// 179.369 us; speedup vs baseline: 1.0850x; 1.0850x over previous
//
#include <hip/hip_runtime.h>
#include <stdint.h>

// ColBERT MaxSim on MI355X (gfx950), round 11.
// scores[b,c] = sum_n max_s dot(qs[b,n,:], ps[c,s,:])
// qs: (64, 32, 128) f32, ps: (64, 1024, 128) f32, out: (64, 64) f32.
//
// R10 (120 us): depth-4 prefetch + Q(128 AGPR) + acc under (256,2) cap ->
// scratch spill (WRITE_SIZE 16 KB -> 4.2 MB). Register budget can't hold
// Q + deep prefetch + 2 waves/SIMD. R11 inverts the wave mapping instead:
//   - block = 16 queries, each wave owns a b-quad (its own qfr[4][2][4]);
//   - all 4 waves walk the SAME s=0..1023 tile sequence -> identical P
//     addresses -> L1 broadcast (3-of-4 waves hit L1), L2 traffic /4;
//   - grid = 64 c x 4 bq = 256 blocks = exactly 1 block/CU; 1 wave/SIMD
//     means per-wave regs are plentiful: depth-4 rolling abuf (64 VGPR) +
//     qfr (128, AGPR) + acc (32) fits with no spill under (256,1);
//   - epilogue is pure shfl per wave (each wave owns its b's exclusively):
//     no LDS, no __syncthreads anywhere.

typedef __bf16 bf16x8 __attribute__((ext_vector_type(8)));
typedef float floatx4 __attribute__((ext_vector_type(4)));

#define QS_N (64u * 32u * 128u)    // 262144
#define PS_N (64u * 1024u * 128u)  // 8388608

__device__ inline unsigned short f2bf(float f) {
  union { float f; uint32_t u; } x{f};
  uint32_t r = (x.u + 0x7FFFu + ((x.u >> 16) & 1u)) >> 16;  // RNE
  return (unsigned short)r;
}

// Fused cvt: first QS_N/4 float4s from qs, rest from ps; qsb = ws, psb = ws + QS_N.
__global__ __launch_bounds__(256) void cvt_kernel(const float* __restrict__ qs,
                                                  const float* __restrict__ ps,
                                                  ushort* __restrict__ outb) {
  const int nq4 = QS_N / 4;
  const int n4 = (QS_N + PS_N) / 4;
  int i = blockIdx.x * 256 + threadIdx.x;
  if (i >= n4) return;
  float4 f;
  if (i < nq4) {
    f = ((const float4*)qs)[i];
  } else {
    f = ((const float4*)ps)[i - nq4];
  }
  ushort4 o;
  o.x = f2bf(f.x); o.y = f2bf(f.y); o.z = f2bf(f.z); o.w = f2bf(f.w);
  ((ushort4*)outb)[i] = o;
}

union FragU { uint4 u; bf16x8 v; };

__device__ inline bf16x8 as_frag(uint4 u) {
  FragU x;
  x.u = u;
  return x.v;
}

// Load 8 bf16 (16 B) as uint4, from pre-converted bf16 or on-the-fly from f32.
template <bool PRECVT>
__device__ inline uint4 load16(const void* p, int off) {
  if (PRECVT) {
    return *(const uint4*)((const ushort*)p + off);
  } else {
    const float* q = (const float*)p + off;
    float4 x = *(const float4*)q;
    float4 y = *(const float4*)(q + 4);
    union { ushort s[8]; uint4 u; } r;
    r.s[0] = f2bf(x.x); r.s[1] = f2bf(x.y); r.s[2] = f2bf(x.z); r.s[3] = f2bf(x.w);
    r.s[4] = f2bf(y.x); r.s[5] = f2bf(y.y); r.s[6] = f2bf(y.z); r.s[7] = f2bf(y.w);
    return r.u;
  }
}

#define ZERO4 {0, 0, 0, 0}

// One 16-row s-tile vs this wave's 4 query blocks x 2 n-halves: 32 MFMAs,
// 8 independent acc chains (4 regs each), k2-major.
#define TILE_COMPUTE(ABUF)                                                      \
  {                                                                             \
    floatx4 acc[4][2];                                                          \
    _Pragma("unroll") for (int b = 0; b < 4; ++b)                               \
      _Pragma("unroll") for (int h = 0; h < 2; ++h)                             \
        acc[b][h] = (floatx4)ZERO4;                                             \
    _Pragma("unroll") for (int k2 = 0; k2 < 4; ++k2) {                          \
      bf16x8 af = as_frag(ABUF[k2]);                                            \
      _Pragma("unroll") for (int b = 0; b < 4; ++b)                             \
        _Pragma("unroll") for (int h = 0; h < 2; ++h)                           \
          acc[b][h] = __builtin_amdgcn_mfma_f32_16x16x32_bf16(                  \
              af, as_frag(qfr[b][h][k2]), acc[b][h], 0, 0, 0);                  \
    }                                                                           \
    _Pragma("unroll") for (int b = 0; b < 4; ++b)                               \
      _Pragma("unroll") for (int h = 0; h < 2; ++h) {                           \
        float m = fmaxf(fmaxf(acc[b][h][0], acc[b][h][1]),                      \
                        fmaxf(acc[b][h][2], acc[b][h][3]));                     \
        vmax[b][h] = fmaxf(vmax[b][h], m);                                      \
      }                                                                         \
  }

template <bool PRECVT>
__global__ __launch_bounds__(256, 1) void maxsim_kernel(const void* __restrict__ qsv,
                                                        const void* __restrict__ psv,
                                                        float* __restrict__ out) {
  const int lane = threadIdx.x & 63;
  const int wave = threadIdx.x >> 6;

  // 256 blocks, round-robin over 8 XCDs -> 32 blocks/XCD = 1/CU.
  // Each XCD owns 8 c's (bf16 P working set 2 MB, L2-resident).
  const int xcd = blockIdx.x & 7;
  const int slot = blockIdx.x >> 3;      // 0..31
  const int c = xcd * 8 + (slot >> 2);   // 0..63
  const int bq = slot & 3;               // 0..3: 16-query group
  const int b0 = bq * 16 + wave * 4;     // this wave's 4 queries

  // 16x16x32 fragment lane pattern: idx16 = lane&15 (A: s-row, B: q-token),
  // koff = (lane>>4)*8; k-step k2 adds k2*32.
  const int idx16 = lane & 15;
  const int koff = (lane >> 4) * 8;

  // This wave's Q fragments: 4 b x 2 n-halves x 4 k-steps = 32 x 16 B.
  // Loaded once, pinned per 32-bit component (compiler parks in AGPRs).
  uint4 qfr[4][2][4];
#pragma unroll
  for (int b = 0; b < 4; ++b)
#pragma unroll
    for (int h = 0; h < 2; ++h)
#pragma unroll
      for (int k2 = 0; k2 < 4; ++k2) {
        const int goff = ((b0 + b) * 32 + h * 16 + idx16) * 128 + k2 * 32 + koff;
        uint4 v = load16<PRECVT>(qsv, goff);
        asm volatile("" : "+v"(v.x), "+v"(v.y), "+v"(v.z), "+v"(v.w));
        qfr[b][h][k2] = v;
      }

  // ALL 4 waves walk the same 64 tiles of 16 doc tokens (s = 0..1023):
  // identical P addresses -> L1 broadcast across waves.
  const int pbase = (c * 1024 + idx16) * 128 + koff;

  // Depth-4 rolling prefetch buffer (64 VGPRs; plenty at 1 wave/SIMD).
  uint4 abuf[4][4];
#pragma unroll
  for (int j = 0; j < 4; ++j)
#pragma unroll
    for (int k2 = 0; k2 < 4; ++k2)
      abuf[j][k2] = load16<PRECVT>(psv, pbase + j * 2048 + k2 * 32);

  float vmax[4][2];
#pragma unroll
  for (int b = 0; b < 4; ++b) {
    vmax[b][0] = -3.4e38f;
    vmax[b][1] = -3.4e38f;
  }

#pragma unroll 1
  for (int t = 0; t < 64; t += 4) {
#pragma unroll
    for (int j = 0; j < 4; ++j) {
      // Compute tile t+j (loads issued 4 tiles = ~650 cyc ago).
      TILE_COMPUTE(abuf[j])
      // Refill with tile t+j+4 (clamp at 63: L1-hot redundant re-read).
      int tn = t + j + 4;
      if (tn > 63) tn = 63;
#pragma unroll
      for (int k2 = 0; k2 < 4; ++k2)
        abuf[j][k2] = load16<PRECVT>(psv, pbase + tn * 2048 + k2 * 32);
    }
  }

  // C/D: col = lane&15 (q-token n within half h), row = (lane>>4)*4 + reg (s).
  // Fold the 4 lane-quads (disjoint s-rows): xor 16, 32 -> every lane holds
  // the max over all s for its (lane&15, h).
#pragma unroll
  for (int b = 0; b < 4; ++b)
#pragma unroll
    for (int h = 0; h < 2; ++h) {
      float v = vmax[b][h];
      v = fmaxf(v, __shfl_xor(v, 16, 64));
      v = fmaxf(v, __shfl_xor(v, 32, 64));
      vmax[b][h] = v;
    }

  // Sum over the 32 query tokens: per b, s = max_h0 + max_h1 summed across
  // the 16 distinct lanes of each xor-16 group (offsets 1,2,4,8).
#pragma unroll
  for (int b = 0; b < 4; ++b) {
    float s = vmax[b][0] + vmax[b][1];
#pragma unroll
    for (int o = 8; o > 0; o >>= 1) s += __shfl_xor(s, o, 64);
    if (lane == 0) out[(b0 + b) * 64 + c] = s;
  }
}

extern "C" void kernel_launch(void* const* d_in, const int* in_sizes, int n_in,
                              void* d_out, int out_size, void* d_ws, size_t ws_size,
                              hipStream_t stream) {
  const float* qs = (const float*)d_in[0];
  const float* ps = (const float*)d_in[1];
  float* out = (float*)d_out;

  const size_t need = (QS_N + PS_N) * sizeof(ushort);  // 16.5 MiB

  if (ws_size >= need) {
    ushort* wsb = (ushort*)d_ws;
    const int n4 = (int)((QS_N + PS_N) / 4);
    cvt_kernel<<<(n4 + 255) / 256, 256, 0, stream>>>(qs, ps, wsb);
    maxsim_kernel<true><<<dim3(256), dim3(256), 0, stream>>>(wsb, wsb + QS_N, out);
  } else {
    maxsim_kernel<false><<<dim3(256), dim3(256), 0, stream>>>(qs, ps, out);
  }
}